// Round 4
// baseline (265.865 us; speedup 1.0000x reference)
//
#include <hip/hip_runtime.h>
#include <math.h>

// Problem constants (fixed by the reference).
#define KCODES 512
#define DDIM   64
#define NROWS  262144
#define ND     ((size_t)NROWS * DDIM)
#define MBLK   64            // rows per block (one 16-row group per 16 lanes)
#define CAP    8             // candidate-list capacity per row
// sigma-scale margin: sigma = dot - c^2/2 = -s_filter/2. R5's proven s-margin
// 1.5e-4 (required 1.14e-4) maps to sigma-margin 7.5e-5 (required 5.7e-5).
// Proven on-HW in R7/R8 (absmax = 0).
#define MARGIN_HALF 7.5e-5f

// ---------------------------------------------------------------------------
// Architecture (R9) = R8 filter math, BARRIER-FREE:
//  * FR (prepacked bf16 hi/lo codebook, 128 KB) is read by every block ->
//    permanently L2-resident, per-pass chunk ~L1-sized. LDS staging of it
//    bought no bandwidth, only 8 block-wide barriers + vmcnt drains + 36 KB
//    LDS. R9 loads B-fragments straight from global (global_load_dwordx4).
//  * Zero __syncthreads. Rows are wave-private (16-lane group per row);
//    lists/win live in per-wave LDS regions; phase transitions use free
//    wave-level s_waitcnt lgkmcnt(0) + sched_barrier.
//  * LDS 37.4 KB -> 4.6 KB; live VGPR state identical to R8's proven 60.
//  * Same sigma-scale (acc init -c^2/2, argMAX), cvt_pk packing, margins,
//    bit-exact numpy-replica fallback as R8 (absmax=0 proven).
// ---------------------------------------------------------------------------

typedef __attribute__((ext_vector_type(8))) short s16x8;
typedef __attribute__((ext_vector_type(4))) float f32x4;
union U4S8 { uint4 u; s16x8 s; };

__device__ __forceinline__ unsigned short bf16_rne(float f) {
    unsigned u = __float_as_uint(f);
    return (unsigned short)((u + 0x7FFFu + ((u >> 16) & 1u)) >> 16);
}
__device__ __forceinline__ float bf16_tof(unsigned short h) {
    return __uint_as_float(((unsigned)h) << 16);
}
__device__ __forceinline__ unsigned cvtpk_bf16(float a, float b) {
    unsigned r;   // lo16 = bf16_rne(a), hi16 = bf16_rne(b)
    asm("v_cvt_pk_bf16_f32 %0, %1, %2" : "=v"(r) : "v"(a), "v"(b));
    return r;
}

// Wave-level phase fence: drain LDS ops, forbid compiler reordering.
__device__ __forceinline__ void wave_fence_lds() {
    asm volatile("s_waitcnt lgkmcnt(0)" ::: "memory");
    __builtin_amdgcn_sched_barrier(0);
}

// numpy pairwise_sum base case for n=64 (verified bit-exact in R2).
__device__ __forceinline__ float np_sumsq64(const float* v) {
    float r[8];
#pragma unroll
    for (int j = 0; j < 8; ++j) r[j] = __fmul_rn(v[j], v[j]);
#pragma unroll
    for (int i = 8; i < 64; i += 8) {
#pragma unroll
        for (int j = 0; j < 8; ++j)
            r[j] = __fadd_rn(r[j], __fmul_rn(v[i + j], v[i + j]));
    }
    float t01 = __fadd_rn(r[0], r[1]);
    float t23 = __fadd_rn(r[2], r[3]);
    float t45 = __fadd_rn(r[4], r[5]);
    float t67 = __fadd_rn(r[6], r[7]);
    return __fadd_rn(__fadd_rn(t01, t23), __fadd_rn(t45, t67));
}

// Streaming np_sumsq (identical op order; for the rare exact path).
__device__ __forceinline__ float np_xs_stream(const float4* __restrict__ xr) {
    float4 u = xr[0], w = xr[1];
    float r0 = __fmul_rn(u.x, u.x), r1 = __fmul_rn(u.y, u.y);
    float r2 = __fmul_rn(u.z, u.z), r3 = __fmul_rn(u.w, u.w);
    float r4 = __fmul_rn(w.x, w.x), r5 = __fmul_rn(w.y, w.y);
    float r6 = __fmul_rn(w.z, w.z), r7 = __fmul_rn(w.w, w.w);
#pragma unroll
    for (int i = 1; i < 8; ++i) {
        u = xr[2 * i]; w = xr[2 * i + 1];
        r0 = __fadd_rn(r0, __fmul_rn(u.x, u.x));
        r1 = __fadd_rn(r1, __fmul_rn(u.y, u.y));
        r2 = __fadd_rn(r2, __fmul_rn(u.z, u.z));
        r3 = __fadd_rn(r3, __fmul_rn(u.w, u.w));
        r4 = __fadd_rn(r4, __fmul_rn(w.x, w.x));
        r5 = __fadd_rn(r5, __fmul_rn(w.y, w.y));
        r6 = __fadd_rn(r6, __fmul_rn(w.z, w.z));
        r7 = __fadd_rn(r7, __fmul_rn(w.w, w.w));
    }
    float t01 = __fadd_rn(r0, r1), t23 = __fadd_rn(r2, r3);
    float t45 = __fadd_rn(r4, r5), t67 = __fadd_rn(r6, r7);
    return __fadd_rn(__fadd_rn(t01, t23), __fadd_rn(t45, t67));
}

// Sequential-FMA dot in ascending dim order (bit-exact vs reference mm).
__device__ __forceinline__ float dot_seq(const float4* __restrict__ xr,
                                         const float* __restrict__ c) {
    const float4* c4 = (const float4*)c;
    float a = 0.f;
#pragma unroll
    for (int i = 0; i < 16; ++i) {
        float4 xv = xr[i];
        float4 cv = c4[i];
        a = __fmaf_rn(xv.x, cv.x, a);
        a = __fmaf_rn(xv.y, cv.y, a);
        a = __fmaf_rn(xv.z, cv.z, a);
        a = __fmaf_rn(xv.w, cv.w, a);
    }
    return a;
}

__device__ __forceinline__ unsigned pair_pack(float va, float vb, int lo) {
    unsigned short ha = bf16_rne(va), hb = bf16_rne(vb);
    if (lo) {
        ha = bf16_rne(va - bf16_tof(ha));
        hb = bf16_rne(vb - bf16_tof(hb));
    }
    return (unsigned)ha | ((unsigned)hb << 16);
}

// Prep (combined, coalesced — R7/R8-proven): blocks 0..31 pack FR
// granule-parallel; blocks 32..33 compute cs (numpy-exact) and csh = -cs/2.
// FR granule g = ((p*8+tt)*4 + fr)*64 + lane, lane = quad*16+mm,
// k = p*128+tt*16+mm, dims d = (fr&1)*32 + quad*8 + j, fr>>1 = lo-part.
__global__ void vq_prep(const float* __restrict__ cb, float* __restrict__ cs,
                        float* __restrict__ csh, unsigned short* __restrict__ FR) {
    int bid = blockIdx.x, t = threadIdx.x;
    if (bid < 32) {
        int g = bid * 256 + t;
        int lane = g & 63, fr = (g >> 6) & 3, tt = (g >> 8) & 7, p = g >> 11;
        int mm = lane & 15, quad = lane >> 4;
        int k = p * 128 + tt * 16 + mm;
        int d0 = (fr & 1) * 32 + quad * 8;
        int lo = fr >> 1;
        const float* src = cb + (size_t)k * DDIM + d0;
        float4 a = *(const float4*)src;
        float4 b = *(const float4*)(src + 4);
        uint4 pk;
        pk.x = pair_pack(a.x, a.y, lo);
        pk.y = pair_pack(a.z, a.w, lo);
        pk.z = pair_pack(b.x, b.y, lo);
        pk.w = pair_pack(b.z, b.w, lo);
        ((uint4*)FR)[g] = pk;
    } else {
        int k = (bid - 32) * 256 + t;
        if (k < KCODES) {
            float v[DDIM];
            const float4* c4 = (const float4*)(cb + (size_t)k * DDIM);
#pragma unroll
            for (int i = 0; i < DDIM / 4; ++i) {
                float4 tv = c4[i];
                v[4 * i + 0] = tv.x; v[4 * i + 1] = tv.y;
                v[4 * i + 2] = tv.z; v[4 * i + 3] = tv.w;
            }
            float s = np_sumsq64(v);
            cs[k] = s;
            csh[k] = -0.5f * s;        // exact
        }
    }
}

// x hi/lo pack via v_cvt_pk (RNE; proven on-HW R7/R8).
__device__ __forceinline__ void pack8(float4 a, float4 b, uint4& hi, uint4& lo) {
    hi.x = cvtpk_bf16(a.x, a.y);
    hi.y = cvtpk_bf16(a.z, a.w);
    hi.z = cvtpk_bf16(b.x, b.y);
    hi.w = cvtpk_bf16(b.z, b.w);
    float r0 = a.x - __uint_as_float(hi.x << 16);
    float r1 = a.y - __uint_as_float(hi.x & 0xffff0000u);
    float r2 = a.z - __uint_as_float(hi.y << 16);
    float r3 = a.w - __uint_as_float(hi.y & 0xffff0000u);
    float r4 = b.x - __uint_as_float(hi.z << 16);
    float r5 = b.y - __uint_as_float(hi.z & 0xffff0000u);
    float r6 = b.z - __uint_as_float(hi.w << 16);
    float r7 = b.w - __uint_as_float(hi.w & 0xffff0000u);
    lo.x = cvtpk_bf16(r0, r1);
    lo.y = cvtpk_bf16(r2, r3);
    lo.z = cvtpk_bf16(r4, r5);
    lo.w = cvtpk_bf16(r6, r7);
}

// LDS (bytes) — all regions wave-private by row ownership:
//   cnt   @    0  (  256)  [64]
//   lstk  @  256  ( 2048)  [64][8] candidate k
//   lsts  @ 2304  ( 2048)  [64][8] candidate sigma
//   win   @ 4352  (  256)  [64]
#define SMEM_BYTES 4608

__launch_bounds__(256, 4)
__global__ void vq_main(const float* __restrict__ x, const float* __restrict__ cb,
                        const float* __restrict__ cs, const float* __restrict__ csh,
                        const unsigned short* __restrict__ FR,
                        float* __restrict__ out) {
    extern __shared__ char smem[];
    int*   cnt  = (int*)  (smem);
    int*   lstk = (int*)  (smem + 256);
    float* lsts = (float*)(smem + 2304);
    int*   win  = (int*)  (smem + 4352);

    const int t    = threadIdx.x;
    const int ln   = t & 63;
    const int wv   = t >> 6;
    const int m    = ln & 15;
    const int quad = ln >> 4;
    const int rowBlk0 = blockIdx.x * MBLK;

    if (ln < 16) cnt[wv * 16 + ln] = 0;

    // A fragments: rows wv*16+m, dims quad*8.. (chunk0) / 32+quad*8.. (chunk1)
    const float* xrow = x + (size_t)(rowBlk0 + wv * 16 + m) * DDIM + quad * 8;
    U4S8 axh0, axh1, axl0, axl1;
    {
        float4 a0 = *(const float4*)(xrow);
        float4 b0 = *(const float4*)(xrow + 4);
        float4 a1 = *(const float4*)(xrow + 32);
        float4 b1 = *(const float4*)(xrow + 36);
        pack8(a0, b0, axh0.u, axl0.u);
        pack8(a1, b1, axh1.u, axl1.u);
    }

    float rm[4] = {-INFINITY, -INFINITY, -INFINITY, -INFINITY};
    const uint4* FRg = (const uint4*)FR;

    for (int p = 0; p < 4; ++p) {
        float chv[8];
#pragma unroll
        for (int tt = 0; tt < 8; ++tt) chv[tt] = csh[p * 128 + tt * 16 + m];

        float s[4][8];
#pragma unroll
        for (int tt = 0; tt < 8; ++tt) {
            // B fragments straight from global (L1/L2-resident FR).
            const uint4* gB = FRg + (size_t)((p * 8 + tt) * 4) * 64 + ln;
            U4S8 bh0, bh1, bl0, bl1;
            bh0.u = gB[0];
            bh1.u = gB[64];
            bl0.u = gB[128];
            bl1.u = gB[192];
            float ch = chv[tt];
            f32x4 acc = {ch, ch, ch, ch};      // sigma-scale: C-in = -c^2/2
            acc = __builtin_amdgcn_mfma_f32_16x16x32_bf16(axh0.s, bh0.s, acc, 0, 0, 0);
            acc = __builtin_amdgcn_mfma_f32_16x16x32_bf16(axh1.s, bh1.s, acc, 0, 0, 0);
            acc = __builtin_amdgcn_mfma_f32_16x16x32_bf16(axl0.s, bh0.s, acc, 0, 0, 0);
            acc = __builtin_amdgcn_mfma_f32_16x16x32_bf16(axl1.s, bh1.s, acc, 0, 0, 0);
            acc = __builtin_amdgcn_mfma_f32_16x16x32_bf16(axh0.s, bl0.s, acc, 0, 0, 0);
            acc = __builtin_amdgcn_mfma_f32_16x16x32_bf16(axh1.s, bl1.s, acc, 0, 0, 0);
#pragma unroll
            for (int r = 0; r < 4; ++r)
                s[r][tt] = acc[r];             // sigma score, argMAX
        }

        // Row-max: in-lane tree + 4-step butterfly over the 16-lane group.
#pragma unroll
        for (int r = 0; r < 4; ++r) {
            float mx = s[r][0];
#pragma unroll
            for (int tt = 1; tt < 8; ++tt) mx = fmaxf(mx, s[r][tt]);
            mx = fmaxf(mx, __shfl_xor(mx, 1, 64));
            mx = fmaxf(mx, __shfl_xor(mx, 2, 64));
            mx = fmaxf(mx, __shfl_xor(mx, 4, 64));
            mx = fmaxf(mx, __shfl_xor(mx, 8, 64));
            rm[r] = fmaxf(rm[r], mx);
        }
        // Collect candidates within running-max - MARGIN (superset of
        // final-max - MARGIN since rm only increases).
#pragma unroll
        for (int r = 0; r < 4; ++r) {
            float thr = rm[r] - MARGIN_HALF;
            int lrow = wv * 16 + quad * 4 + r;
#pragma unroll
            for (int tt = 0; tt < 8; ++tt) {
                if (s[r][tt] >= thr) {
                    int pos = atomicAdd(&cnt[lrow], 1);
                    if (pos < CAP) {
                        lstk[lrow * CAP + pos] = p * 128 + tt * 16 + m;
                        lsts[lrow * CAP + pos] = s[r][tt];
                    }
                }
            }
        }
    }

    wave_fence_lds();   // lists visible to the wave's selector lanes

    // Final selection: lane m<4 of each group owns row wv*16+quad*4+m.
    if (m < 4) {
        int lrow = wv * 16 + quad * 4 + m;
        float rmf = (m == 0) ? rm[0] : (m == 1) ? rm[1] : (m == 2) ? rm[2] : rm[3];
        float thr = rmf - MARGIN_HALF;
        int c = cnt[lrow];
        int kb;
        const float4* xr = (const float4*)(x + (size_t)(rowBlk0 + lrow) * DDIM);
        if (c <= CAP) {
            int nc = 0, k1 = 0;
            for (int i = 0; i < c; ++i)
                if (lsts[lrow * CAP + i] >= thr) { ++nc; k1 = lstk[lrow * CAP + i]; }
            if (nc == 1) {
                kb = k1;
            } else {
                // Bit-exact numpy replica over surviving candidates
                // (tie -> lowest k = numpy first occurrence).
                float xs = np_xs_stream(xr);
                float db = INFINITY; kb = 0x7fffffff;
                for (int i = 0; i < c; ++i) {
                    if (lsts[lrow * CAP + i] >= thr) {
                        int k = lstk[lrow * CAP + i];
                        float a = dot_seq(xr, cb + (size_t)k * DDIM);
                        float d = __fadd_rn(__fadd_rn(xs, cs[k]), __fmul_rn(-2.0f, a));
                        if (d < db || (d == db && k < kb)) { db = d; kb = k; }
                    }
                }
            }
        } else {
            // Overflow: exact scan of all 512 (ascending + strict '<').
            float xs = np_xs_stream(xr);
            float db = INFINITY; kb = 0;
            for (int k = 0; k < KCODES; ++k) {
                float a = dot_seq(xr, cb + (size_t)k * DDIM);
                float d = __fadd_rn(__fadd_rn(xs, cs[k]), __fmul_rn(-2.0f, a));
                if (d < db) { db = d; kb = k; }
            }
        }
        win[lrow] = kb;
        out[2 * ND + (size_t)(rowBlk0 + lrow)] = (float)kb;
    }

    wave_fence_lds();   // win visible to the wave's epilogue lanes

    // Epilogue (per-wave): z_q = z_q_bar = codebook[win] for the wave's
    // 16 rows; 64 lanes cover 4 rows x 16 float4-chunks = 1 KB contiguous
    // per iteration.
#pragma unroll
    for (int i = 0; i < 4; ++i) {
        int g   = i * 64 + ln;                // 0..255 granules of this wave
        int row = wv * 16 + (g >> 4), cc = g & 15;
        int kb  = win[row];
        float4 v = *(const float4*)(cb + (size_t)kb * DDIM + cc * 4);
        size_t gr = (size_t)(rowBlk0 + row) * DDIM + (size_t)cc * 4;
        *(float4*)(out + gr) = v;
        *(float4*)(out + ND + gr) = v;
    }
}

extern "C" void kernel_launch(void* const* d_in, const int* in_sizes, int n_in,
                              void* d_out, int out_size, void* d_ws, size_t ws_size,
                              hipStream_t stream) {
    const float* z  = (const float*)d_in[0];   // [N, D] fp32
    const float* cb = (const float*)d_in[1];   // [K, D] fp32
    float* out = (float*)d_out;                // [N*D | N*D | N] fp32
    float* cs          = (float*)d_ws;                          // 512 f32 exact
    float* csh         = (float*)((char*)d_ws + 2048);          // 512 f32 (-cs/2)
    unsigned short* FR = (unsigned short*)((char*)d_ws + 4096); // 128 KB frag-ordered

    (void)hipFuncSetAttribute((const void*)vq_main,
                              hipFuncAttributeMaxDynamicSharedMemorySize,
                              SMEM_BYTES);
    vq_prep<<<34, 256, 0, stream>>>(cb, cs, csh, FR);
    vq_main<<<NROWS / MBLK, 256, SMEM_BYTES, stream>>>(z, cb, cs, csh, FR, out);
}